// Round 8
// baseline (242.633 us; speedup 1.0000x reference)
//
#include <hip/hip_runtime.h>
#include <hip/hip_bf16.h>

#define Nn 50000
#define DEG 16
#define IN_F 512
#define HID 128
#define OUT_F 64
#define SLOPE 0.2f

typedef __attribute__((ext_vector_type(8))) short bf16x8;
typedef __attribute__((ext_vector_type(4))) float f32x4;
typedef __attribute__((ext_vector_type(4))) unsigned int u32x4;

__device__ __forceinline__ unsigned short f2bf(float f) {
    return __builtin_bit_cast(unsigned short, __float2bfloat16(f));
}
__device__ __forceinline__ float bf2f(unsigned short u) {
    return __bfloat162float(__builtin_bit_cast(__hip_bfloat16, u));
}
__device__ __forceinline__ void async_copy16(const void* g, void* l) {
    __builtin_amdgcn_global_load_lds(
        (const __attribute__((address_space(1))) unsigned int*)g,
        (__attribute__((address_space(3))) unsigned int*)l, 16, 0, 0);
}

// ---------- prep ----------
// W12 = W1@W2 stored flat-transposed [col][K] bf16 (direct L2 fragment reads
// in gemm1_lin -- the 64KB table is L2-hot chip-wide).
// u1 = W1@al1, v1 = W1@ar1 (fp32), c2 = b1@W2 (fp32).
__global__ void __launch_bounds__(256) prep_kernel(
        const float* __restrict__ W1, const float* __restrict__ W2,
        const float* __restrict__ al1, const float* __restrict__ ar1,
        const float* __restrict__ b1, const int* __restrict__ row_ptr,
        unsigned short* __restrict__ w12t, float* __restrict__ uv,
        float* __restrict__ c2v, int* __restrict__ flag64) {
    const int tid = threadIdx.x;
    const int lane = tid & 63;
    const int w = tid >> 6;
    const int k = blockIdx.x * 4 + w;          // 0..511
    if (blockIdx.x == 0 && tid == 0) {
        // int32 layout: row_ptr words = [0,16,32,...]; int64: [0,0,16,0,...]
        *flag64 = (row_ptr[1] == DEG) ? 0 : 1;
    }
    const float* w1row = W1 + (size_t)k * HID;

    float acc = 0.f;
    #pragma unroll 8
    for (int j = 0; j < HID; ++j)
        acc += w1row[j] * W2[j * OUT_F + lane];
    w12t[(size_t)lane * IN_F + k] = f2bf(acc);     // B^T layout [col][k]

    float pu = w1row[lane] * al1[lane] + w1row[lane + 64] * al1[lane + 64];
    float pv = w1row[lane] * ar1[lane] + w1row[lane + 64] * ar1[lane + 64];
    #pragma unroll
    for (int m = 1; m < 64; m <<= 1) {
        pu += __shfl_xor(pu, m);
        pv += __shfl_xor(pv, m);
    }
    if (lane == 0) { uv[k] = pu; uv[IN_F + k] = pv; }

    if (blockIdx.x == 0 && w == 0) {
        float cacc = 0.f;
        #pragma unroll 8
        for (int j = 0; j < HID; ++j) cacc += b1[j] * W2[j * OUT_F + lane];
        c2v[lane] = cacc;
    }
}

// ---------- layer-1: LINEAR-stream GEMM: g = x @ W12 ----------
// The 2 TB/s x-stream invariant held across 6 structures whose common trait
// was 2KB-strided chunk reads. This block shape makes the x-read perfectly
// linear: 16 consecutive rows x 2KB = ONE contiguous 32KB global region per
// block (3125 blocks tile x sequentially, fill-style), staged via 32
// lane-linear 1KB global_load_lds. Full K in one shot -> ONE stage barrier
// per block (vs 8-16 chunk drains). 4 waves split K 4-ways (K=128 each),
// partials reduced through LDS (R2's verified reduction); the reduction
// buffer ALIASES the A-tile (union, barrier-separated) -> LDS 33KB ->
// 4 blocks/CU. B fragments direct from the L2-hot 64KB w12t (R1/R2's
// verified indexing). A XOR-swizzle applied via the global source
// (permutes 16B blocks inside 128B lines only -- linearity preserved);
// ds_read applies the same XOR -> conflict-free b128. el/er exact fp32.
template<int K>
__global__ void __launch_bounds__(256) gemm1_lin(
        const float* __restrict__ Af, const unsigned short* __restrict__ w12t,
        const float* __restrict__ uv,
        unsigned short* __restrict__ G, float* __restrict__ el,
        float* __restrict__ er, int M) {
    __shared__ char ldsbuf[16 * 512 * 4];      // 32 KB union: As | red
    __shared__ float redl[4][16];
    __shared__ float redr[4][16];
    float* As = (float*)ldsbuf;                // [16][512] fp32, swizzled
    typedef float redt[64][20];
    redt* red = (redt*)ldsbuf;                 // [4][64][20] partials

    const int tid  = threadIdx.x;
    const int lane = tid & 63;
    const int w    = tid >> 6;
    const int ln   = lane & 15, q = lane >> 4;
    const int mb   = blockIdx.x * 16;          // 50000 % 16 == 0: no guards

    // ---- stage 16 rows x 2KB = 32KB fully contiguous; wave w: 8 x 1KB ----
    // DMA j covers row j>>1, half j&1; lane's 16B block b = (j&1)*64 + lane.
    // Source block pre-XORed with (row&7): LDS[row][blk] = x[row][blk^c],
    // XOR flips only low 3 bits -> stays inside the same 1KB span.
    #pragma unroll
    for (int i = 0; i < 8; ++i) {
        int j   = w * 8 + i;
        int row = j >> 1;
        int b   = (j & 1) * 64 + lane;
        int c   = row & 7;
        const float* src = Af + (size_t)(mb + row) * K + ((b ^ c) << 2);
        async_copy16(src, ldsbuf + j * 1024);
    }
    __syncthreads();                           // drains DMA (vmcnt 0)

    // ---- compute: wave w owns K-slice [w*128, w*128+128) ----
    f32x4 acc[4] = {};
    float sl = 0.f, sr = 0.f;
    const int c7 = ln & 7;
    #pragma unroll
    for (int ks = 0; ks < 4; ++ks) {
        const int B0 = w * 32 + ks * 8 + q * 2;    // 16B-block index in row
        f32x4 a0 = *(const f32x4*)&As[ln * 512 + ((B0 ^ c7) << 2)];
        f32x4 a1 = *(const f32x4*)&As[ln * 512 + (((B0 + 1) ^ c7) << 2)];
        const int ko = w * 128 + ks * 32 + q * 8;
        f32x4 u0 = *(const f32x4*)(uv + ko);
        f32x4 u1 = *(const f32x4*)(uv + ko + 4);
        f32x4 v0 = *(const f32x4*)(uv + K + ko);
        f32x4 v1 = *(const f32x4*)(uv + K + ko + 4);
        bf16x8 af;
        #pragma unroll
        for (int jj = 0; jj < 4; ++jj) {
            af[jj]     = (short)f2bf(a0[jj]);
            af[jj + 4] = (short)f2bf(a1[jj]);
            sl += a0[jj] * u0[jj] + a1[jj] * u1[jj];
            sr += a0[jj] * v0[jj] + a1[jj] * v1[jj];
        }
        #pragma unroll
        for (int nt = 0; nt < 4; ++nt) {
            bf16x8 bfr = *(const bf16x8*)&w12t[(size_t)(nt * 16 + ln) * K + ko];
            acc[nt] = __builtin_amdgcn_mfma_f32_16x16x32_bf16(af, bfr, acc[nt], 0, 0, 0);
        }
    }
    __syncthreads();                           // all waves done reading As

    // ---- split-K reduction (R2-verified): red aliases As ----
    // D layout: col = ln', row = q*4 + r  ->  red[w][col][row]
    #pragma unroll
    for (int nt = 0; nt < 4; ++nt)
        *(f32x4*)&red[w][nt * 16 + ln][q * 4] = acc[nt];

    sl += __shfl_xor(sl, 16); sl += __shfl_xor(sl, 32);
    sr += __shfl_xor(sr, 16); sr += __shfl_xor(sr, 32);
    if (q == 0) { redl[w][ln] = sl; redr[w][ln] = sr; }
    __syncthreads();

    const int cc = tid & 63;
    const int r0 = (tid >> 6) * 4;
    f32x4 s = *(const f32x4*)&red[0][cc][r0];
    #pragma unroll
    for (int ww = 1; ww < 4; ++ww) {
        f32x4 p = *(const f32x4*)&red[ww][cc][r0];
        s += p;
    }
    #pragma unroll
    for (int j = 0; j < 4; ++j)
        G[(size_t)(mb + r0 + j) * OUT_F + cc] = f2bf(s[j]);

    if (tid < 16) {
        el[mb + tid] = redl[0][tid] + redl[1][tid] + redl[2][tid] + redl[3][tid];
        er[mb + tid] = redr[0][tid] + redr[1][tid] + redr[2][tid] + redr[3][tid];
    }
}

// ---------- aggregation (both layers): 2 nodes per 16-lane group ----------
// (byte-identical to R7 -- measured neutral vs R4's variant, keep)
template<int MODE>
__global__ void __launch_bounds__(256) agg_k(
        const int* __restrict__ col, const int* __restrict__ flag64,
        const float* __restrict__ el, const float* __restrict__ er,
        const unsigned short* __restrict__ Hs, const float* __restrict__ addv,
        const float* __restrict__ alv, const float* __restrict__ arv,
        unsigned short* __restrict__ Ho, float* __restrict__ elo,
        float* __restrict__ ero, float* __restrict__ Fo) {
    const int tid  = threadIdx.x;
    const int lane = tid & 63;
    const int w    = tid >> 6;
    const int ln   = lane & 15, q = lane >> 4;
    const int g16  = w * 4 + q;                 // group 0..15 in block
    const int nA   = blockIdx.x * 32 + g16 * 2;
    const int nB   = nA + 1;
    const int nAc  = nA < Nn ? nA : Nn - 1;     // clamp for tail block loads
    const int nBc  = nB < Nn ? nB : Nn - 1;
    const int use64 = *flag64;

    // ---- softmax for both nodes (lane ln = edge index) ----
    int eA = nAc * DEG + ln, eB = nBc * DEG + ln;
    int srcA = use64 ? (int)((const long long*)col)[eA] : col[eA];
    int srcB = use64 ? (int)((const long long*)col)[eB] : col[eB];
    float scA = el[nAc] + er[srcA];
    float scB = el[nBc] + er[srcB];
    scA = scA >= 0.f ? scA : SLOPE * scA;
    scB = scB >= 0.f ? scB : SLOPE * scB;
    float mxA = scA, mxB = scB;
    #pragma unroll
    for (int m = 1; m < 16; m <<= 1) {
        mxA = fmaxf(mxA, __shfl_xor(mxA, m, 16));
        mxB = fmaxf(mxB, __shfl_xor(mxB, m, 16));
    }
    float exA = __expf(scA - mxA), exB = __expf(scB - mxB);
    float smA = exA, smB = exB;
    #pragma unroll
    for (int m = 1; m < 16; m <<= 1) {
        smA += __shfl_xor(smA, m, 16);
        smB += __shfl_xor(smB, m, 16);
    }
    float alA = exA / smA, alB = exB / smB;

    // ---- gather: issue ALL 16 row loads first, then accumulate ----
    const int half = ln >> 3, cc = ln & 7;
    bf16x8 hA[8], hB[8];
    #pragma unroll
    for (int p = 0; p < 8; ++p) {
        int sjA = __shfl(srcA, p * 2 + half, 16);
        int sjB = __shfl(srcB, p * 2 + half, 16);
        hA[p] = *(const bf16x8*)&Hs[(size_t)sjA * OUT_F + cc * 8];
        hB[p] = *(const bf16x8*)&Hs[(size_t)sjB * OUT_F + cc * 8];
    }
    float aA[8] = {}, aB[8] = {};
    #pragma unroll
    for (int p = 0; p < 8; ++p) {
        float wA = __shfl(alA, p * 2 + half, 16);
        float wB = __shfl(alB, p * 2 + half, 16);
        #pragma unroll
        for (int c = 0; c < 8; ++c) {
            aA[c] += wA * bf2f((unsigned short)hA[p][c]);
            aB[c] += wB * bf2f((unsigned short)hB[p][c]);
        }
    }
    #pragma unroll
    for (int c = 0; c < 8; ++c) {
        aA[c] += __shfl_xor(aA[c], 8, 16);     // combine the two edge-halves
        aB[c] += __shfl_xor(aB[c], 8, 16);
        float ad = addv[cc * 8 + c];
        aA[c] += ad;
        aB[c] += ad;
    }

    if (MODE == 0) {
        float plA = 0.f, prA = 0.f, plB = 0.f, prB = 0.f;
        #pragma unroll
        for (int c = 0; c < 8; ++c) {
            float av = alv[cc * 8 + c], bv = arv[cc * 8 + c];
            plA += aA[c] * av;  prA += aA[c] * bv;
            plB += aB[c] * av;  prB += aB[c] * bv;
        }
        #pragma unroll
        for (int m = 1; m < 8; m <<= 1) {
            plA += __shfl_xor(plA, m, 16);  prA += __shfl_xor(prA, m, 16);
            plB += __shfl_xor(plB, m, 16);  prB += __shfl_xor(prB, m, 16);
        }
        if (ln == 0) {
            if (nA < Nn) { elo[nA] = plA; ero[nA] = prA; }
            if (nB < Nn) { elo[nB] = plB; ero[nB] = prB; }
        }
        if (half == 0) {
            unsigned int pkA[4], pkB[4];
            #pragma unroll
            for (int c = 0; c < 4; ++c) {
                pkA[c] = (unsigned int)f2bf(aA[2 * c]) |
                         ((unsigned int)f2bf(aA[2 * c + 1]) << 16);
                pkB[c] = (unsigned int)f2bf(aB[2 * c]) |
                         ((unsigned int)f2bf(aB[2 * c + 1]) << 16);
            }
            if (nA < Nn) *(u32x4*)&Ho[(size_t)nA * OUT_F + cc * 8] = *(u32x4*)pkA;
            if (nB < Nn) *(u32x4*)&Ho[(size_t)nB * OUT_F + cc * 8] = *(u32x4*)pkB;
        }
    } else {
        if (half == 0) {
            f32x4 oA0, oA1, oB0, oB1;
            #pragma unroll
            for (int c = 0; c < 4; ++c) {
                oA0[c] = aA[c]; oA1[c] = aA[c + 4];
                oB0[c] = aB[c]; oB1[c] = aB[c + 4];
            }
            if (nA < Nn) {
                *(f32x4*)&Fo[(size_t)nA * OUT_F + cc * 8]     = oA0;
                *(f32x4*)&Fo[(size_t)nA * OUT_F + cc * 8 + 4] = oA1;
            }
            if (nB < Nn) {
                *(f32x4*)&Fo[(size_t)nB * OUT_F + cc * 8]     = oB0;
                *(f32x4*)&Fo[(size_t)nB * OUT_F + cc * 8 + 4] = oB1;
            }
        }
    }
}

extern "C" void kernel_launch(void* const* d_in, const int* in_sizes, int n_in,
                              void* d_out, int out_size, void* d_ws, size_t ws_size,
                              hipStream_t stream) {
    const int*   row_ptr = (const int*)d_in[0];
    const int*   col_idx = (const int*)d_in[1];
    const float* x   = (const float*)d_in[2];
    const float* W1  = (const float*)d_in[3];
    const float* al1 = (const float*)d_in[4];
    const float* ar1 = (const float*)d_in[5];
    const float* b1  = (const float*)d_in[6];
    const float* W2  = (const float*)d_in[7];
    const float* al2 = (const float*)d_in[8];
    const float* ar2 = (const float*)d_in[9];
    const float* b2  = (const float*)d_in[10];
    float* out = (float*)d_out;

    float* ws = (float*)d_ws;
    unsigned short* g   = (unsigned short*)ws;                 // N*64 bf16
    unsigned short* h2b = (unsigned short*)(ws + 1600000);     // N*64 bf16
    float* el1 = ws + 3200000;
    float* er1 = ws + 3250000;
    float* el2 = ws + 3300000;
    float* er2 = ws + 3350000;
    unsigned short* w12t = (unsigned short*)(ws + 3400000);    // 64*512 bf16 flat B^T
    float* uv  = ws + 3420000;                                 // u1[512], v1[512]
    float* c2v = ws + 3421024;                                 // 64
    int* flag64 = (int*)(ws + 3421100);

    prep_kernel<<<128, 256, 0, stream>>>(
        W1, W2, al1, ar1, b1, row_ptr, w12t, uv, c2v, flag64);

    gemm1_lin<IN_F><<<Nn / 16, 256, 0, stream>>>(
        x, w12t, uv, g, el1, er1, Nn);

    agg_k<0><<<(Nn + 31) / 32, 256, 0, stream>>>(
        col_idx, flag64, el1, er1, g, c2v, al2, ar2, h2b, el2, er2, nullptr);

    agg_k<1><<<(Nn + 31) / 32, 256, 0, stream>>>(
        col_idx, flag64, el2, er2, h2b, b2, nullptr, nullptr,
        nullptr, nullptr, nullptr, out);
}

// Round 9
// 240.892 us; speedup vs baseline: 1.0072x; 1.0072x over previous
//
#include <hip/hip_runtime.h>
#include <hip/hip_bf16.h>

#define Nn 50000
#define DEG 16
#define IN_F 512
#define HID 128
#define OUT_F 64
#define SLOPE 0.2f

typedef __attribute__((ext_vector_type(8))) short bf16x8;
typedef __attribute__((ext_vector_type(4))) float f32x4;
typedef __attribute__((ext_vector_type(4))) unsigned int u32x4;

__device__ __forceinline__ unsigned short f2bf(float f) {
    return __builtin_bit_cast(unsigned short, __float2bfloat16(f));
}
__device__ __forceinline__ float bf2f(unsigned short u) {
    return __bfloat162float(__builtin_bit_cast(__hip_bfloat16, u));
}
__device__ __forceinline__ void async_copy16(const void* g, void* l) {
    __builtin_amdgcn_global_load_lds(
        (const __attribute__((address_space(1))) unsigned int*)g,
        (__attribute__((address_space(3))) unsigned int*)l, 16, 0, 0);
}

// ---------- prep (R4/R7 layout, verbatim) ----------
__global__ void __launch_bounds__(256) prep_kernel(
        const float* __restrict__ W1, const float* __restrict__ W2,
        const float* __restrict__ al1, const float* __restrict__ ar1,
        const float* __restrict__ b1, const int* __restrict__ row_ptr,
        unsigned short* __restrict__ w12c, float* __restrict__ uv,
        float* __restrict__ c2v, int* __restrict__ flag64) {
    const int tid = threadIdx.x;
    const int lane = tid & 63;
    const int w = tid >> 6;
    const int k = blockIdx.x * 4 + w;          // 0..511
    if (blockIdx.x == 0 && tid == 0) {
        *flag64 = (row_ptr[1] == DEG) ? 0 : 1;
    }
    const float* w1row = W1 + (size_t)k * HID;

    float acc = 0.f;
    #pragma unroll 8
    for (int j = 0; j < HID; ++j)
        acc += w1row[j] * W2[j * OUT_F + lane];
    {   // 128-k chunk-major swizzled store (8192 ushorts = 16 KB per chunk)
        int ch = k >> 7, kin = k & 127;
        int bsrc = kin >> 3, j = kin & 7;
        int bdst = bsrc ^ (lane & 7);
        w12c[ch * 8192 + lane * 128 + bdst * 8 + j] = f2bf(acc);
    }

    float pu = w1row[lane] * al1[lane] + w1row[lane + 64] * al1[lane + 64];
    float pv = w1row[lane] * ar1[lane] + w1row[lane + 64] * ar1[lane + 64];
    #pragma unroll
    for (int m = 1; m < 64; m <<= 1) {
        pu += __shfl_xor(pu, m);
        pv += __shfl_xor(pv, m);
    }
    if (lane == 0) { uv[k] = pu; uv[IN_F + k] = pv; }

    if (blockIdx.x == 0 && w == 0) {
        float cacc = 0.f;
        #pragma unroll 8
        for (int j = 0; j < HID; ++j) cacc += b1[j] * W2[j * OUT_F + lane];
        c2v[lane] = cacc;
    }
}

// ---------- layer-1: R4's tiled GEMM (best of 7 measured structures) ----------
// Byte-identical to R7 except the epilogue stores g as TWO column-half
// tables G0/G1 ([n][32] bf16, 3.2MB each) so the aggregation's gather
// working set fits the 4MB per-XCD L2.
template<int K>
__global__ void __launch_bounds__(256) gemm1_tiled(
        const float* __restrict__ Af, const unsigned short* __restrict__ w12c,
        const float* __restrict__ uv,
        unsigned short* __restrict__ G0, unsigned short* __restrict__ G1,
        float* __restrict__ el, float* __restrict__ er, int M) {
    constexpr int NCH = K / 128;
    __shared__ float As[64 * 128];             // 32 KB, swizzled
    __shared__ unsigned short Bs[64 * 128];    // 16 KB, swizzled

    const int tid  = threadIdx.x;
    const int lane = tid & 63;
    const int w    = tid >> 6;
    const int ln   = lane & 15, q = lane >> 4;
    const int r2   = lane >> 5, b = lane & 31;
    const int mb   = blockIdx.x * 64;

    f32x4 acc[4] = {};
    float sl = 0.f, sr = 0.f;

    for (int ch = 0; ch < NCH; ++ch) {
        const char* gb = (const char*)w12c + ch * 16384;
        #pragma unroll
        for (int i = 0; i < 4; ++i) {
            int slot = w * 4 + i;
            async_copy16(gb + slot * 1024 + lane * 16, (char*)Bs + slot * 1024);
        }
        #pragma unroll
        for (int i = 0; i < 8; ++i) {
            int rl = w * 16 + i * 2 + r2;
            int rg = mb + rl; if (rg > M - 1) rg = M - 1;
            int c  = rl & 7;
            const float* src = Af + (size_t)rg * K + ch * 128 + ((b ^ c) << 2);
            async_copy16(src, (char*)As + (size_t)(w * 16 + i * 2) * 512);
        }
        __syncthreads();                       // drains vmcnt incl. the DMA

        const float* up = uv + ch * 128;
        const float* vp = uv + K + ch * 128;
        const int c = ln & 7;
        #pragma unroll
        for (int ks = 0; ks < 4; ++ks) {
            const int b0 = ks * 8 + q * 2;
            f32x4 a0 = *(const f32x4*)&As[(w * 16 + ln) * 128 + ((b0 ^ c) << 2)];
            f32x4 a1 = *(const f32x4*)&As[(w * 16 + ln) * 128 + (((b0 + 1) ^ c) << 2)];
            f32x4 u0 = *(const f32x4*)(up + ks * 32 + q * 8);
            f32x4 u1 = *(const f32x4*)(up + ks * 32 + q * 8 + 4);
            f32x4 v0 = *(const f32x4*)(vp + ks * 32 + q * 8);
            f32x4 v1 = *(const f32x4*)(vp + ks * 32 + q * 8 + 4);
            bf16x8 af;
            #pragma unroll
            for (int jj = 0; jj < 4; ++jj) {
                af[jj]     = (short)f2bf(a0[jj]);
                af[jj + 4] = (short)f2bf(a1[jj]);
                sl += a0[jj] * u0[jj] + a1[jj] * u1[jj];
                sr += a0[jj] * v0[jj] + a1[jj] * v1[jj];
            }
            #pragma unroll
            for (int nt = 0; nt < 4; ++nt) {
                const int bb = ks * 4 + q;
                bf16x8 bfr = *(const bf16x8*)&Bs[(nt * 16 + ln) * 128 + ((bb ^ c) << 3)];
                acc[nt] = __builtin_amdgcn_mfma_f32_16x16x32_bf16(af, bfr, acc[nt], 0, 0, 0);
            }
        }
        __syncthreads();                       // before next chunk overwrites
    }

    sl += __shfl_xor(sl, 16); sl += __shfl_xor(sl, 32);
    sr += __shfl_xor(sr, 16); sr += __shfl_xor(sr, 32);
    const int rowe = mb + w * 16 + ln;
    if (q == 0 && rowe < M) { el[rowe] = sl; er[rowe] = sr; }

    // D layout: col = nt*16+ln, row = q*4 + r; split-store into half-tables
    #pragma unroll
    for (int r = 0; r < 4; ++r) {
        int grow = mb + w * 16 + q * 4 + r;
        if (grow < M) {
            #pragma unroll
            for (int nt = 0; nt < 4; ++nt) {
                unsigned short* T = (nt < 2) ? G0 : G1;
                T[(size_t)grow * 32 + (nt & 1) * 16 + ln] = f2bf(acc[nt][r]);
            }
        }
    }
}

// ---------- aggregation: column-split two-pass, L2-resident gathers ----------
// 2 nodes per 16-lane group, 32 nodes/block. Row-half = 64B: lane ln handles
// edge-slot es=ln>>2 and 16B chunk cc=ln&3 -> 4 edges x 4 chunks in parallel,
// p-loop 4 iters covers DEG=16. Edge-slot reduce: shfl_xor {4,8}.
// HALF 0: softmax (exact, as before) + store alpha (bitwise reuse in pass B)
//         + gather half-0 table; HALF 1: load alpha + gather half-1.
// MODE 0: +c2 half, write h2 half-table + el2/er2 (partial in A, final in B).
// MODE 1: +bias2 half, write fp32 out cols [HALF*32, HALF*32+32).
template<int MODE, int HALF>
__global__ void __launch_bounds__(256) agg_half(
        const int* __restrict__ col, const int* __restrict__ flag64,
        const float* __restrict__ el, const float* __restrict__ er,
        const unsigned short* __restrict__ Hs, const float* __restrict__ addv,
        const float* __restrict__ alv, const float* __restrict__ arv,
        float* __restrict__ alpha,
        unsigned short* __restrict__ Ho, float* __restrict__ elo,
        float* __restrict__ ero, float* __restrict__ Fo) {
    const int tid  = threadIdx.x;
    const int lane = tid & 63;
    const int w    = tid >> 6;
    const int ln   = lane & 15, q = lane >> 4;
    const int g16  = w * 4 + q;
    const int nA   = blockIdx.x * 32 + g16 * 2;
    const int nB   = nA + 1;
    const int nAc  = nA < Nn ? nA : Nn - 1;
    const int nBc  = nB < Nn ? nB : Nn - 1;
    const int use64 = *flag64;

    int eA = nAc * DEG + ln, eB = nBc * DEG + ln;
    int srcA = use64 ? (int)((const long long*)col)[eA] : col[eA];
    int srcB = use64 ? (int)((const long long*)col)[eB] : col[eB];

    float alA, alB;
    if (HALF == 0) {
        // ---- softmax for both nodes (lane ln = edge index) ----
        float scA = el[nAc] + er[srcA];
        float scB = el[nBc] + er[srcB];
        scA = scA >= 0.f ? scA : SLOPE * scA;
        scB = scB >= 0.f ? scB : SLOPE * scB;
        float mxA = scA, mxB = scB;
        #pragma unroll
        for (int m = 1; m < 16; m <<= 1) {
            mxA = fmaxf(mxA, __shfl_xor(mxA, m, 16));
            mxB = fmaxf(mxB, __shfl_xor(mxB, m, 16));
        }
        float exA = __expf(scA - mxA), exB = __expf(scB - mxB);
        float smA = exA, smB = exB;
        #pragma unroll
        for (int m = 1; m < 16; m <<= 1) {
            smA += __shfl_xor(smA, m, 16);
            smB += __shfl_xor(smB, m, 16);
        }
        alA = exA / smA;  alB = exB / smB;
        if (nA < Nn) alpha[eA] = alA;          // 64B/node, nodes adjacent
        if (nB < Nn) alpha[eB] = alB;
    } else {
        alA = alpha[eA];
        alB = alpha[eB];
    }

    // ---- gather: 4 edges x 4x16B chunks, 8 loads in flight ----
    const int es = ln >> 2, cc = ln & 3;
    bf16x8 hA[4], hB[4];
    #pragma unroll
    for (int p = 0; p < 4; ++p) {
        int sjA = __shfl(srcA, p * 4 + es, 16);
        int sjB = __shfl(srcB, p * 4 + es, 16);
        hA[p] = *(const bf16x8*)&Hs[(size_t)sjA * 32 + cc * 8];
        hB[p] = *(const bf16x8*)&Hs[(size_t)sjB * 32 + cc * 8];
    }
    float aA[8] = {}, aB[8] = {};
    #pragma unroll
    for (int p = 0; p < 4; ++p) {
        float wA = __shfl(alA, p * 4 + es, 16);
        float wB = __shfl(alB, p * 4 + es, 16);
        #pragma unroll
        for (int c = 0; c < 8; ++c) {
            aA[c] += wA * bf2f((unsigned short)hA[p][c]);
            aB[c] += wB * bf2f((unsigned short)hB[p][c]);
        }
    }
    #pragma unroll
    for (int c = 0; c < 8; ++c) {
        aA[c] += __shfl_xor(aA[c], 4, 16);     // reduce over 4 edge-slots
        aA[c] += __shfl_xor(aA[c], 8, 16);
        aB[c] += __shfl_xor(aB[c], 4, 16);
        aB[c] += __shfl_xor(aB[c], 8, 16);
        float ad = addv[HALF * 32 + cc * 8 + c];
        aA[c] += ad;
        aB[c] += ad;
    }

    if (MODE == 0) {
        float plA = 0.f, prA = 0.f, plB = 0.f, prB = 0.f;
        #pragma unroll
        for (int c = 0; c < 8; ++c) {
            float av = alv[HALF * 32 + cc * 8 + c];
            float bv = arv[HALF * 32 + cc * 8 + c];
            plA += aA[c] * av;  prA += aA[c] * bv;
            plB += aB[c] * av;  prB += aB[c] * bv;
        }
        plA += __shfl_xor(plA, 1, 16); plA += __shfl_xor(plA, 2, 16);
        prA += __shfl_xor(prA, 1, 16); prA += __shfl_xor(prA, 2, 16);
        plB += __shfl_xor(plB, 1, 16); plB += __shfl_xor(plB, 2, 16);
        prB += __shfl_xor(prB, 1, 16); prB += __shfl_xor(prB, 2, 16);
        if (ln == 0) {
            if (HALF == 0) {
                if (nA < Nn) { elo[nA] = plA; ero[nA] = prA; }
                if (nB < Nn) { elo[nB] = plB; ero[nB] = prB; }
            } else {
                if (nA < Nn) { elo[nA] += plA; ero[nA] += prA; }
                if (nB < Nn) { elo[nB] += plB; ero[nB] += prB; }
            }
        }
        if (es == 0) {                          // lanes 0..3: 4 x 16B = 64B
            unsigned int pkA[4], pkB[4];
            #pragma unroll
            for (int c = 0; c < 4; ++c) {
                pkA[c] = (unsigned int)f2bf(aA[2 * c]) |
                         ((unsigned int)f2bf(aA[2 * c + 1]) << 16);
                pkB[c] = (unsigned int)f2bf(aB[2 * c]) |
                         ((unsigned int)f2bf(aB[2 * c + 1]) << 16);
            }
            if (nA < Nn) *(u32x4*)&Ho[(size_t)nA * 32 + cc * 8] = *(u32x4*)pkA;
            if (nB < Nn) *(u32x4*)&Ho[(size_t)nB * 32 + cc * 8] = *(u32x4*)pkB;
        }
    } else {
        if (es == 0) {
            f32x4 oA0, oA1, oB0, oB1;
            #pragma unroll
            for (int c = 0; c < 4; ++c) {
                oA0[c] = aA[c]; oA1[c] = aA[c + 4];
                oB0[c] = aB[c]; oB1[c] = aB[c + 4];
            }
            if (nA < Nn) {
                *(f32x4*)&Fo[(size_t)nA * OUT_F + HALF * 32 + cc * 8]     = oA0;
                *(f32x4*)&Fo[(size_t)nA * OUT_F + HALF * 32 + cc * 8 + 4] = oA1;
            }
            if (nB < Nn) {
                *(f32x4*)&Fo[(size_t)nB * OUT_F + HALF * 32 + cc * 8]     = oB0;
                *(f32x4*)&Fo[(size_t)nB * OUT_F + HALF * 32 + cc * 8 + 4] = oB1;
            }
        }
    }
}

extern "C" void kernel_launch(void* const* d_in, const int* in_sizes, int n_in,
                              void* d_out, int out_size, void* d_ws, size_t ws_size,
                              hipStream_t stream) {
    const int*   row_ptr = (const int*)d_in[0];
    const int*   col_idx = (const int*)d_in[1];
    const float* x   = (const float*)d_in[2];
    const float* W1  = (const float*)d_in[3];
    const float* al1 = (const float*)d_in[4];
    const float* ar1 = (const float*)d_in[5];
    const float* b1  = (const float*)d_in[6];
    const float* W2  = (const float*)d_in[7];
    const float* al2 = (const float*)d_in[8];
    const float* ar2 = (const float*)d_in[9];
    const float* b2  = (const float*)d_in[10];
    float* out = (float*)d_out;

    float* ws = (float*)d_ws;
    unsigned short* g0   = (unsigned short*)ws;                // N*32 bf16 (3.2MB)
    unsigned short* g1   = (unsigned short*)(ws + 800000);     // N*32 bf16
    unsigned short* h2b0 = (unsigned short*)(ws + 1600000);    // N*32 bf16
    unsigned short* h2b1 = (unsigned short*)(ws + 2400000);    // N*32 bf16
    float* el1 = ws + 3200000;
    float* er1 = ws + 3250000;
    float* el2 = ws + 3300000;
    float* er2 = ws + 3350000;
    float* alpha1 = ws + 3400000;                              // E fp32
    float* alpha2 = ws + 4200000;                              // E fp32
    unsigned short* w12c = (unsigned short*)(ws + 5000000);    // chunked+swizzled
    float* uv  = ws + 5020000;                                 // u1[512], v1[512]
    float* c2v = ws + 5021100;                                 // 64
    int* flag64 = (int*)(ws + 5021200);

    prep_kernel<<<128, 256, 0, stream>>>(
        W1, W2, al1, ar1, b1, row_ptr, w12c, uv, c2v, flag64);

    gemm1_tiled<IN_F><<<(Nn + 63) / 64, 256, 0, stream>>>(
        x, w12c, uv, g0, g1, el1, er1, Nn);

    agg_half<0, 0><<<(Nn + 31) / 32, 256, 0, stream>>>(
        col_idx, flag64, el1, er1, g0, c2v, al2, ar2, alpha1,
        h2b0, el2, er2, nullptr);
    agg_half<0, 1><<<(Nn + 31) / 32, 256, 0, stream>>>(
        col_idx, flag64, el1, er1, g1, c2v, al2, ar2, alpha1,
        h2b1, el2, er2, nullptr);

    agg_half<1, 0><<<(Nn + 31) / 32, 256, 0, stream>>>(
        col_idx, flag64, el2, er2, h2b0, b2, nullptr, nullptr, alpha2,
        nullptr, nullptr, nullptr, out);
    agg_half<1, 1><<<(Nn + 31) / 32, 256, 0, stream>>>(
        col_idx, flag64, el2, er2, h2b1, b2, nullptr, nullptr, alpha2,
        nullptr, nullptr, nullptr, out);
}

// Round 10
// 221.375 us; speedup vs baseline: 1.0960x; 1.0882x over previous
//
#include <hip/hip_runtime.h>
#include <hip/hip_bf16.h>

#define Nn 50000
#define DEG 16
#define IN_F 512
#define HID 128
#define OUT_F 64
#define SLOPE 0.2f

typedef __attribute__((ext_vector_type(8))) short bf16x8;
typedef __attribute__((ext_vector_type(4))) float f32x4;
typedef __attribute__((ext_vector_type(4))) unsigned int u32x4;

__device__ __forceinline__ unsigned short f2bf(float f) {
    return __builtin_bit_cast(unsigned short, __float2bfloat16(f));
}
__device__ __forceinline__ float bf2f(unsigned short u) {
    return __bfloat162float(__builtin_bit_cast(__hip_bfloat16, u));
}
__device__ __forceinline__ void async_copy16(const void* g, void* l) {
    __builtin_amdgcn_global_load_lds(
        (const __attribute__((address_space(1))) unsigned int*)g,
        (__attribute__((address_space(3))) unsigned int*)l, 16, 0, 0);
}

// ---------- prep (R4 layout) ----------
// W12 = W1@W2, stored 128-k-chunk-major + XOR-pre-swizzled
// (w12c[ch][col][bsrc ^ (col&7)][8] bf16, 16KB chunks) for gemm1_tiled's
// lane-linear async staging + conflict-lean b128 fragment reads.
// u1 = W1@al1, v1 = W1@ar1 (fp32), c2 = b1@W2 (fp32).
__global__ void __launch_bounds__(256) prep_kernel(
        const float* __restrict__ W1, const float* __restrict__ W2,
        const float* __restrict__ al1, const float* __restrict__ ar1,
        const float* __restrict__ b1, const int* __restrict__ row_ptr,
        unsigned short* __restrict__ w12c, float* __restrict__ uv,
        float* __restrict__ c2v, int* __restrict__ flag64) {
    const int tid = threadIdx.x;
    const int lane = tid & 63;
    const int w = tid >> 6;
    const int k = blockIdx.x * 4 + w;          // 0..511
    if (blockIdx.x == 0 && tid == 0) {
        // int32 layout: row_ptr words = [0,16,32,...]; int64: [0,0,16,0,...]
        *flag64 = (row_ptr[1] == DEG) ? 0 : 1;
    }
    const float* w1row = W1 + (size_t)k * HID;

    float acc = 0.f;
    #pragma unroll 8
    for (int j = 0; j < HID; ++j)
        acc += w1row[j] * W2[j * OUT_F + lane];
    {   // 128-k chunk-major swizzled store (8192 ushorts = 16 KB per chunk)
        int ch = k >> 7, kin = k & 127;
        int bsrc = kin >> 3, j = kin & 7;
        int bdst = bsrc ^ (lane & 7);
        w12c[ch * 8192 + lane * 128 + bdst * 8 + j] = f2bf(acc);
    }

    float pu = w1row[lane] * al1[lane] + w1row[lane + 64] * al1[lane + 64];
    float pv = w1row[lane] * ar1[lane] + w1row[lane + 64] * ar1[lane + 64];
    #pragma unroll
    for (int m = 1; m < 64; m <<= 1) {
        pu += __shfl_xor(pu, m);
        pv += __shfl_xor(pv, m);
    }
    if (lane == 0) { uv[k] = pu; uv[IN_F + k] = pv; }

    if (blockIdx.x == 0 && w == 0) {
        float cacc = 0.f;
        #pragma unroll 8
        for (int j = 0; j < HID; ++j) cacc += b1[j] * W2[j * OUT_F + lane];
        c2v[lane] = cacc;
    }
}

// ---------- layer-1: R4's tiled GEMM (best of 8 measured structures) ----------
// Block = 64 rows x 64 cols, 4 waves each owning 16 rows. K staged in
// 128-chunks: A fp32 [64][128] (32KB) + B bf16 [64][128] (16KB), both via
// global_load_lds width=16 lane-linear 1KB transfers; single-buffer,
// __syncthreads-drained (measured ~48-51us vs 62 for dbuf/counted/linear
// variants -- the structure sweep is complete, do not re-pipeline).
// XOR swizzle (block ^ (row&7)) pre-applied on the global source; frag
// ds_read_b128 applies the same XOR. el/er exact fp32 from the staged A
// fragments. LDS 48KB -> 3 blocks/CU.
template<int K>
__global__ void __launch_bounds__(256) gemm1_tiled(
        const float* __restrict__ Af, const unsigned short* __restrict__ w12c,
        const float* __restrict__ uv,
        unsigned short* __restrict__ G, float* __restrict__ el,
        float* __restrict__ er, int M) {
    constexpr int NCH = K / 128;
    __shared__ float As[64 * 128];             // 32 KB, swizzled
    __shared__ unsigned short Bs[64 * 128];    // 16 KB, swizzled

    const int tid  = threadIdx.x;
    const int lane = tid & 63;
    const int w    = tid >> 6;
    const int ln   = lane & 15, q = lane >> 4;
    const int r2   = lane >> 5, b = lane & 31;
    const int mb   = blockIdx.x * 64;

    f32x4 acc[4] = {};
    float sl = 0.f, sr = 0.f;

    for (int ch = 0; ch < NCH; ++ch) {
        // ---- stage B chunk: wave w covers cols [w*16, w*16+16) = 4 x 1KB ----
        const char* gb = (const char*)w12c + ch * 16384;
        #pragma unroll
        for (int i = 0; i < 4; ++i) {
            int slot = w * 4 + i;
            async_copy16(gb + slot * 1024 + lane * 16, (char*)Bs + slot * 1024);
        }
        // ---- stage A chunk: wave w rows [w*16, w*16+16) = 8 x 1KB ----
        // dest base uniform; lane's dest = base + lane*16 = row(r2), block(b).
        // source pre-XORed so LDS[row][blk] = x[row][blk ^ (row&7)].
        #pragma unroll
        for (int i = 0; i < 8; ++i) {
            int rl = w * 16 + i * 2 + r2;
            int rg = mb + rl; if (rg > M - 1) rg = M - 1;
            int c  = rl & 7;
            const float* src = Af + (size_t)rg * K + ch * 128 + ((b ^ c) << 2);
            async_copy16(src, (char*)As + (size_t)(w * 16 + i * 2) * 512);
        }
        __syncthreads();                       // drains vmcnt incl. the DMA

        // ---- compute: 16 MFMA per chunk per wave ----
        const float* up = uv + ch * 128;
        const float* vp = uv + K + ch * 128;
        const int c = ln & 7;
        #pragma unroll
        for (int ks = 0; ks < 4; ++ks) {
            const int b0 = ks * 8 + q * 2;
            f32x4 a0 = *(const f32x4*)&As[(w * 16 + ln) * 128 + ((b0 ^ c) << 2)];
            f32x4 a1 = *(const f32x4*)&As[(w * 16 + ln) * 128 + (((b0 + 1) ^ c) << 2)];
            f32x4 u0 = *(const f32x4*)(up + ks * 32 + q * 8);
            f32x4 u1 = *(const f32x4*)(up + ks * 32 + q * 8 + 4);
            f32x4 v0 = *(const f32x4*)(vp + ks * 32 + q * 8);
            f32x4 v1 = *(const f32x4*)(vp + ks * 32 + q * 8 + 4);
            bf16x8 af;
            #pragma unroll
            for (int jj = 0; jj < 4; ++jj) {
                af[jj]     = (short)f2bf(a0[jj]);
                af[jj + 4] = (short)f2bf(a1[jj]);
                sl += a0[jj] * u0[jj] + a1[jj] * u1[jj];
                sr += a0[jj] * v0[jj] + a1[jj] * v1[jj];
            }
            #pragma unroll
            for (int nt = 0; nt < 4; ++nt) {
                const int bb = ks * 4 + q;
                bf16x8 bfr = *(const bf16x8*)&Bs[(nt * 16 + ln) * 128 + ((bb ^ c) << 3)];
                acc[nt] = __builtin_amdgcn_mfma_f32_16x16x32_bf16(af, bfr, acc[nt], 0, 0, 0);
            }
        }
        __syncthreads();                       // before next chunk overwrites
    }

    // el/er: lane holds row w*16+ln's k-partials across q; reduce over q
    sl += __shfl_xor(sl, 16); sl += __shfl_xor(sl, 32);
    sr += __shfl_xor(sr, 16); sr += __shfl_xor(sr, 32);
    const int rowe = mb + w * 16 + ln;
    if (q == 0 && rowe < M) { el[rowe] = sl; er[rowe] = sr; }

    // D layout: col = ln (within nt tile), row = q*4 + r
    #pragma unroll
    for (int r = 0; r < 4; ++r) {
        int grow = mb + w * 16 + q * 4 + r;
        if (grow < M) {
            #pragma unroll
            for (int nt = 0; nt < 4; ++nt)
                G[(size_t)grow * OUT_F + nt * 16 + ln] = f2bf(acc[nt][r]);
        }
    }
}

// ---------- aggregation (both layers): 2 nodes per 16-lane group ----------
// Explicit load/compute split: all 16 gather loads issued into registers
// before any accumulation (forces 16 outstanding VMEM per lane).
// 1-pass full-row gather -- measured best of 3 agg structures (2-pass
// column-split regressed +18us in R9).
// MODE 0: +c2, write bf16 h2 + el2/er2.   MODE 1: +bias2, write fp32 out.
template<int MODE>
__global__ void __launch_bounds__(256) agg_k(
        const int* __restrict__ col, const int* __restrict__ flag64,
        const float* __restrict__ el, const float* __restrict__ er,
        const unsigned short* __restrict__ Hs, const float* __restrict__ addv,
        const float* __restrict__ alv, const float* __restrict__ arv,
        unsigned short* __restrict__ Ho, float* __restrict__ elo,
        float* __restrict__ ero, float* __restrict__ Fo) {
    const int tid  = threadIdx.x;
    const int lane = tid & 63;
    const int w    = tid >> 6;
    const int ln   = lane & 15, q = lane >> 4;
    const int g16  = w * 4 + q;                 // group 0..15 in block
    const int nA   = blockIdx.x * 32 + g16 * 2;
    const int nB   = nA + 1;
    const int nAc  = nA < Nn ? nA : Nn - 1;     // clamp for tail block loads
    const int nBc  = nB < Nn ? nB : Nn - 1;
    const int use64 = *flag64;

    // ---- softmax for both nodes (lane ln = edge index) ----
    int eA = nAc * DEG + ln, eB = nBc * DEG + ln;
    int srcA = use64 ? (int)((const long long*)col)[eA] : col[eA];
    int srcB = use64 ? (int)((const long long*)col)[eB] : col[eB];
    float scA = el[nAc] + er[srcA];
    float scB = el[nBc] + er[srcB];
    scA = scA >= 0.f ? scA : SLOPE * scA;
    scB = scB >= 0.f ? scB : SLOPE * scB;
    float mxA = scA, mxB = scB;
    #pragma unroll
    for (int m = 1; m < 16; m <<= 1) {
        mxA = fmaxf(mxA, __shfl_xor(mxA, m, 16));
        mxB = fmaxf(mxB, __shfl_xor(mxB, m, 16));
    }
    float exA = __expf(scA - mxA), exB = __expf(scB - mxB);
    float smA = exA, smB = exB;
    #pragma unroll
    for (int m = 1; m < 16; m <<= 1) {
        smA += __shfl_xor(smA, m, 16);
        smB += __shfl_xor(smB, m, 16);
    }
    float alA = exA / smA, alB = exB / smB;

    // ---- gather: issue ALL 16 row loads first, then accumulate ----
    const int half = ln >> 3, cc = ln & 7;
    bf16x8 hA[8], hB[8];
    #pragma unroll
    for (int p = 0; p < 8; ++p) {
        int sjA = __shfl(srcA, p * 2 + half, 16);
        int sjB = __shfl(srcB, p * 2 + half, 16);
        hA[p] = *(const bf16x8*)&Hs[(size_t)sjA * OUT_F + cc * 8];
        hB[p] = *(const bf16x8*)&Hs[(size_t)sjB * OUT_F + cc * 8];
    }
    float aA[8] = {}, aB[8] = {};
    #pragma unroll
    for (int p = 0; p < 8; ++p) {
        float wA = __shfl(alA, p * 2 + half, 16);
        float wB = __shfl(alB, p * 2 + half, 16);
        #pragma unroll
        for (int c = 0; c < 8; ++c) {
            aA[c] += wA * bf2f((unsigned short)hA[p][c]);
            aB[c] += wB * bf2f((unsigned short)hB[p][c]);
        }
    }
    #pragma unroll
    for (int c = 0; c < 8; ++c) {
        aA[c] += __shfl_xor(aA[c], 8, 16);     // combine the two edge-halves
        aB[c] += __shfl_xor(aB[c], 8, 16);
        float ad = addv[cc * 8 + c];
        aA[c] += ad;
        aB[c] += ad;
    }

    if (MODE == 0) {
        float plA = 0.f, prA = 0.f, plB = 0.f, prB = 0.f;
        #pragma unroll
        for (int c = 0; c < 8; ++c) {
            float av = alv[cc * 8 + c], bv = arv[cc * 8 + c];
            plA += aA[c] * av;  prA += aA[c] * bv;
            plB += aB[c] * av;  prB += aB[c] * bv;
        }
        #pragma unroll
        for (int m = 1; m < 8; m <<= 1) {
            plA += __shfl_xor(plA, m, 16);  prA += __shfl_xor(prA, m, 16);
            plB += __shfl_xor(plB, m, 16);  prB += __shfl_xor(prB, m, 16);
        }
        if (ln == 0) {
            if (nA < Nn) { elo[nA] = plA; ero[nA] = prA; }
            if (nB < Nn) { elo[nB] = plB; ero[nB] = prB; }
        }
        if (half == 0) {
            unsigned int pkA[4], pkB[4];
            #pragma unroll
            for (int c = 0; c < 4; ++c) {
                pkA[c] = (unsigned int)f2bf(aA[2 * c]) |
                         ((unsigned int)f2bf(aA[2 * c + 1]) << 16);
                pkB[c] = (unsigned int)f2bf(aB[2 * c]) |
                         ((unsigned int)f2bf(aB[2 * c + 1]) << 16);
            }
            if (nA < Nn) *(u32x4*)&Ho[(size_t)nA * OUT_F + cc * 8] = *(u32x4*)pkA;
            if (nB < Nn) *(u32x4*)&Ho[(size_t)nB * OUT_F + cc * 8] = *(u32x4*)pkB;
        }
    } else {
        if (half == 0) {
            f32x4 oA0, oA1, oB0, oB1;
            #pragma unroll
            for (int c = 0; c < 4; ++c) {
                oA0[c] = aA[c]; oA1[c] = aA[c + 4];
                oB0[c] = aB[c]; oB1[c] = aB[c + 4];
            }
            if (nA < Nn) {
                *(f32x4*)&Fo[(size_t)nA * OUT_F + cc * 8]     = oA0;
                *(f32x4*)&Fo[(size_t)nA * OUT_F + cc * 8 + 4] = oA1;
            }
            if (nB < Nn) {
                *(f32x4*)&Fo[(size_t)nB * OUT_F + cc * 8]     = oB0;
                *(f32x4*)&Fo[(size_t)nB * OUT_F + cc * 8 + 4] = oB1;
            }
        }
    }
}

extern "C" void kernel_launch(void* const* d_in, const int* in_sizes, int n_in,
                              void* d_out, int out_size, void* d_ws, size_t ws_size,
                              hipStream_t stream) {
    const int*   row_ptr = (const int*)d_in[0];
    const int*   col_idx = (const int*)d_in[1];
    const float* x   = (const float*)d_in[2];
    const float* W1  = (const float*)d_in[3];
    const float* al1 = (const float*)d_in[4];
    const float* ar1 = (const float*)d_in[5];
    const float* b1  = (const float*)d_in[6];
    const float* W2  = (const float*)d_in[7];
    const float* al2 = (const float*)d_in[8];
    const float* ar2 = (const float*)d_in[9];
    const float* b2  = (const float*)d_in[10];
    float* out = (float*)d_out;

    float* ws = (float*)d_ws;
    unsigned short* g   = (unsigned short*)ws;                 // N*64 bf16
    unsigned short* h2b = (unsigned short*)(ws + 1600000);     // N*64 bf16
    float* el1 = ws + 3200000;
    float* er1 = ws + 3250000;
    float* el2 = ws + 3300000;
    float* er2 = ws + 3350000;
    unsigned short* w12c = (unsigned short*)(ws + 3400000);    // 64*512 bf16, chunked+swizzled
    float* uv  = ws + 3420000;                                 // u1[512], v1[512]
    float* c2v = ws + 3421024;                                 // 64
    int* flag64 = (int*)(ws + 3421100);

    prep_kernel<<<128, 256, 0, stream>>>(
        W1, W2, al1, ar1, b1, row_ptr, w12c, uv, c2v, flag64);

    gemm1_tiled<IN_F><<<(Nn + 63) / 64, 256, 0, stream>>>(
        x, w12c, uv, g, el1, er1, Nn);

    agg_k<0><<<(Nn + 31) / 32, 256, 0, stream>>>(
        col_idx, flag64, el1, er1, g, c2v, al2, ar2, h2b, el2, er2, nullptr);

    agg_k<1><<<(Nn + 31) / 32, 256, 0, stream>>>(
        col_idx, flag64, el2, er2, h2b, b2, nullptr, nullptr,
        nullptr, nullptr, nullptr, out);
}